// Round 6
// baseline (344.590 us; speedup 1.0000x reference)
//
#include <hip/hip_runtime.h>

typedef unsigned short u16;
typedef u16 u16x8 __attribute__((ext_vector_type(8)));
typedef __bf16 bf16x8 __attribute__((ext_vector_type(8)));
typedef float f32x4 __attribute__((ext_vector_type(4)));

#define NPIX 100352           // 32*56*56
#define KTOT 2304             // 3*3*256
#define IMG_PAD (58 * 58 * 256)

static __device__ __forceinline__ u16 f2bf(float f) {
  unsigned u = __float_as_uint(f);
  return (u16)((u + 0x7fffu + ((u >> 16) & 1u)) >> 16);
}

static __device__ __forceinline__ void gld_lds16(const u16* g, u16* l) {
  __builtin_amdgcn_global_load_lds(
      (const __attribute__((address_space(1))) void*)g,
      (__attribute__((address_space(3))) void*)l, 16, 0, 0);
}

// A-panel k-offset (u16) for K-tile kt: halo offset of khw + 64*(kt&3)
static __device__ __forceinline__ int ka_of(int kt) {
  const int khw = kt >> 2;                 // 0..8
  const int q = (khw * 11) >> 5;           // khw/3 for 0..8
  const int r = khw - q * 3;               // khw%3
  return (q * 58 + r - 59) * 256 + (kt & 3) * 64;
}

// ---------- scale[f] = sum_k |w[k][f]| ----------
__global__ void scale_accum_k(const float* __restrict__ w, float* __restrict__ scale) {
  const int t = threadIdx.x;
  const float* p = w + (long)blockIdx.x * 64 * 256 + t;
  float acc = 0.f;
#pragma unroll
  for (int e = 0; e < 64; ++e) acc += fabsf(p[(long)e * 256]);
  atomicAdd(&scale[t], acc);
}

// ---------- wp[f][k] = bf16( scale[f]/2304 * sign(w[k][f]) * mask[k][f] ) ----------
__global__ void pack_w_k(const float* __restrict__ w, const float* __restrict__ mask,
                         const float* __restrict__ ssum, u16* __restrict__ wp) {
  __shared__ u16 t[128][33];
  const int k0 = blockIdx.x * 32;
  const int f0 = blockIdx.y * 128;
  const int tid = threadIdx.x;
#pragma unroll
  for (int i = 0; i < 16; ++i) {
    int idx = tid + i * 256;
    int kk = idx >> 7;
    int ff = idx & 127;
    long g = (long)(k0 + kk) * 256 + f0 + ff;
    float wv = w[g];
    float mv = mask[g];
    float sc = ssum[f0 + ff] * (1.0f / 2304.0f);
    float sg = (wv > 0.f) ? 1.f : ((wv < 0.f) ? -1.f : 0.f);
    t[ff][kk] = f2bf(sc * sg * mv);
  }
  __syncthreads();
#pragma unroll
  for (int i = 0; i < 8; ++i) {
    int idx = tid + i * 256;
    int row = idx >> 4;
    int c = idx & 15;
    unsigned v = (unsigned)t[row][2 * c] | ((unsigned)t[row][2 * c + 1] << 16);
    *(unsigned*)(wp + (long)(f0 + row) * KTOT + k0 + 2 * c) = v;
  }
}

// ---------- x fp32 -> bf16 padded [32][58][58][256] — division-free 2D grid ----------
__global__ __launch_bounds__(256) void fill_xpad3_k(const float* __restrict__ x,
                                                    u16* __restrict__ xp) {
  const int img = blockIdx.y;
  const int ph = blockIdx.x;                       // 0..57
  u16* rowp = xp + ((img * 58 + ph) * 58) * 256;
  const bool irow = (ph >= 1 && ph <= 56);
  const float* xrow = x + ((long)img * 3136 + (ph - 1) * 56) * 256;
  for (int i = threadIdx.x; i < 58 * 32; i += 256) {
    const int pw = i >> 5;                         // 0..57
    const int c8 = (i & 31) * 8;                   // channel chunk base
    u16x8 v = {0, 0, 0, 0, 0, 0, 0, 0};
    if (irow && pw >= 1 && pw <= 56) {
      const float* s = xrow + (pw - 1) * 256 + c8;
      float4 a = *(const float4*)s;
      float4 b = *(const float4*)(s + 4);
      v[0] = f2bf(a.x); v[1] = f2bf(a.y); v[2] = f2bf(a.z); v[3] = f2bf(a.w);
      v[4] = f2bf(b.x); v[5] = f2bf(b.y); v[6] = f2bf(b.z); v[7] = f2bf(b.w);
    }
    *(u16x8*)(rowp + pw * 256 + c8) = v;
  }
}

// ---------- 256x256 8-phase conv, A triple-buffer / B double-buffer (160 KB LDS) ----
// C[M=100352,N=256] = A[M,K=2304]*B^T. 512 thr = 8 waves (2M x 4N), per-wave C 128x64.
// Prefetch distance = 2 K-tiles for BOTH operands. Per 4-phase group kt:
//   p0: ds_read B(all)+A q0; stage A(kt+2)h0 -> As[(kt+2)%3]
//   p1: ds_read A q1;        stage A(kt+2)h1 + B(kt+2)h0 -> Bs[kt%2]
//   p2: ds_read A q2;        stage B(kt+2)h1
//   p3: ds_read A q3;        s_waitcnt vmcnt(8)   (completes group kt-1's 8 loads,
//                             issued 7-9 phases earlier ~= HBM-miss latency)
// each phase: raw barrier, setprio(1), 16 MFMA, setprio(0), raw barrier.
// Hazards: B(kt+2) overwrites Bs[kt%2] from p1 — safe: all 8 B ds_reads are consumed
// by p0's MFMA cluster before p0's closing barrier. A(kt+2) overwrites As[(kt-1)%3],
// last read at group kt-1 p3 — safe from group kt p0. Period-6 unroll makes all
// buffer indices compile-time (6 == 0 mod 3 and mod 2).
#define STAGE_A3(kt, h, buf) do { const int _ka = ka_of(kt); \
    gld_lds16(aptr[(h)*2]     + _ka, (buf) + ldso[(h)*2]); \
    gld_lds16(aptr[(h)*2 + 1] + _ka, (buf) + ldso[(h)*2 + 1]); } while (0)
#define STAGE_B3(kt, h, buf) do { const int _kb = (kt) * 64; \
    gld_lds16(bptr[(h)*2]     + _kb, (buf) + ldso[(h)*2]); \
    gld_lds16(bptr[(h)*2 + 1] + _kb, (buf) + ldso[(h)*2 + 1]); } while (0)
// combined stage for phase 1 (A half 1 + B half 0) — single statement
#define STAGE_AB3(kt, Aw, Bw) do { STAGE_A3(kt, 1, Aw); STAGE_B3(kt, 0, Bw); } while (0)

// one phase: reads (B at pp==0), stage hook, barrier, 16 MFMA, barrier
#define PHASE(pp, ABUF, BBUF, STAGE_STMT, WAIT_STMT) do {                         \
    if ((pp) == 0) {                                                              \
      _Pragma("unroll") for (int ni = 0; ni < 4; ++ni)                            \
        _Pragma("unroll") for (int ct = 0; ct < 2; ++ct)                          \
          bv[ni][ct] = *(const bf16x8*)((BBUF) + bB + pcq[ct] + ni * 1024);       \
    }                                                                             \
    bf16x8 av[2][2];                                                              \
    _Pragma("unroll") for (int f = 0; f < 2; ++f)                                 \
      _Pragma("unroll") for (int ct = 0; ct < 2; ++ct)                            \
        av[f][ct] = *(const bf16x8*)((ABUF) + aB + pcq[ct] + (pp) * 2048 + f * 1024); \
    STAGE_STMT;                                                                   \
    WAIT_STMT;                                                                    \
    __builtin_amdgcn_s_barrier();                                                 \
    asm volatile("" ::: "memory");                                                \
    __builtin_amdgcn_s_setprio(1);                                                \
    _Pragma("unroll") for (int ct = 0; ct < 2; ++ct)                              \
      _Pragma("unroll") for (int f = 0; f < 2; ++f)                               \
        _Pragma("unroll") for (int ni = 0; ni < 4; ++ni)                          \
          acc[(pp) * 2 + f][ni] = __builtin_amdgcn_mfma_f32_16x16x32_bf16(        \
              av[f][ct], bv[ni][ct], acc[(pp) * 2 + f][ni], 0, 0, 0);             \
    __builtin_amdgcn_s_setprio(0);                                                \
    asm volatile("" ::: "memory");                                                \
    __builtin_amdgcn_s_barrier();                                                 \
    asm volatile("" ::: "memory");                                                \
  } while (0)

#define VMC8 asm volatile("s_waitcnt vmcnt(8)" ::: "memory")
#define VMC0 asm volatile("s_waitcnt vmcnt(0)" ::: "memory")
#define NOSTMT do { } while (0)

__global__ __launch_bounds__(512, 2) void conv_gemm9_k(
    const u16* __restrict__ xpad, const u16* __restrict__ wp, float* __restrict__ out) {
  __shared__ u16 As[3][256 * 64];   // 96 KB
  __shared__ u16 Bs[2][256 * 64];   // 64 KB  (total 160 KB = full CU LDS)

  const int tid = threadIdx.x;
  const int lane = tid & 63;
  const int wid = tid >> 6;         // 0..7

  // grid 392 = 8 XCD x 49, bijective swizzle (n0 == 0; B shared by all blocks)
  const int orig = blockIdx.x;
  const int swz = (orig & 7) * 49 + (orig >> 3);
  const int m0 = swz * 256;

  // --- staging map: octet o = (q>>1)*16 + (q&1)*8 + wid covers rows [o*8, o*8+8)
  const int lsub = lane >> 3;                       // 0..7 row-in-octet
  const int lc = (lane & 7) ^ lsub;                 // logical chunk (XOR swizzle)
  const u16* aptr[4];
  const u16* bptr[4];
  int ldso[4];
#pragma unroll
  for (int q = 0; q < 4; ++q) {
    const int o = (q >> 1) * 16 + (q & 1) * 8 + wid;   // 0..31
    const int row = o * 8 + lsub;                      // 0..255
    const int m = m0 + row;
    const int img = m / 3136, pix = m % 3136;
    aptr[q] = xpad + (long)img * IMG_PAD + ((pix / 56 + 1) * 58 + (pix % 56) + 1) * 256 + lc * 8;
    bptr[q] = wp + (long)row * KTOT + lc * 8;
    ldso[q] = o * 512;                                 // u16 units; DMA adds lane*16B
  }

  // --- MFMA lane mapping (verified layout)
  const int lm = lane & 15, kq = lane >> 4;
  const int wm = wid >> 2, wn = wid & 3;
  int pcq[2];
  pcq[0] = (kq ^ (lm & 7)) * 8;
  pcq[1] = ((4 + kq) ^ (lm & 7)) * 8;
  const int aB = (wm * 128 + lm) * 64;   // + pp*2048 + f*1024 + pcq[ct]
  const int bB = (wn * 64 + lm) * 64;    // + ni*1024 + pcq[ct]

  f32x4 acc[8][4] = {};
  bf16x8 bv[4][2];

  // --- prologue: A(0),B(0),A(1),B(1); vmcnt(8) completes kt=0 pair, leaves kt=1 pair
  STAGE_A3(0, 0, As[0]); STAGE_A3(0, 1, As[0]);
  STAGE_B3(0, 0, Bs[0]); STAGE_B3(0, 1, Bs[0]);
  STAGE_A3(1, 0, As[1]); STAGE_A3(1, 1, As[1]);
  STAGE_B3(1, 0, Bs[1]); STAGE_B3(1, 1, Bs[1]);
  VMC8;
  __builtin_amdgcn_s_barrier();
  asm volatile("" ::: "memory");

  // --- main: 5 periods of 6 K-tiles (kt 0..29), all stage kt+2
  for (int J6 = 0; J6 < 5; ++J6) {
    const int kt0 = J6 * 6;
#pragma unroll
    for (int u = 0; u < 6; ++u) {
      const int kt = kt0 + u;
      u16* Ar = As[u % 3];            // read buf (kt%3 == u%3)
      u16* Br = Bs[u & 1];            // read buf (kt%2 == u%2)
      u16* Aw = As[(u + 2) % 3];      // write buf for A(kt+2)
      u16* Bw = Bs[u & 1];            // write buf for B(kt+2) (== read buf; safe, see hdr)
      PHASE(0, Ar, Br, STAGE_A3(kt + 2, 0, Aw), NOSTMT);
      PHASE(1, Ar, Br, STAGE_AB3(kt + 2, Aw, Bw), NOSTMT);
      PHASE(2, Ar, Br, STAGE_B3(kt + 2, 1, Bw), NOSTMT);
      PHASE(3, Ar, Br, NOSTMT, VMC8);
    }
  }

  // --- epilogue: kt 30..35 (u 0..5); stage only while kt+2 <= 35 (u <= 3)
#pragma unroll
  for (int u = 0; u < 6; ++u) {
    const int kt = 30 + u;
    u16* Ar = As[u % 3];
    u16* Br = Bs[u & 1];
    u16* Aw = As[(u + 2) % 3];
    u16* Bw = Bs[u & 1];
    if (u < 4) {
      PHASE(0, Ar, Br, STAGE_A3(kt + 2, 0, Aw), NOSTMT);
      PHASE(1, Ar, Br, STAGE_AB3(kt + 2, Aw, Bw), NOSTMT);
      PHASE(2, Ar, Br, STAGE_B3(kt + 2, 1, Bw), NOSTMT);
      PHASE(3, Ar, Br, NOSTMT, VMC8);
    } else if (u == 4) {
      PHASE(0, Ar, Br, NOSTMT, NOSTMT);
      PHASE(1, Ar, Br, NOSTMT, NOSTMT);
      PHASE(2, Ar, Br, NOSTMT, NOSTMT);
      PHASE(3, Ar, Br, NOSTMT, VMC0);
    } else {
      PHASE(0, Ar, Br, NOSTMT, NOSTMT);
      PHASE(1, Ar, Br, NOSTMT, NOSTMT);
      PHASE(2, Ar, Br, NOSTMT, NOSTMT);
      PHASE(3, Ar, Br, NOSTMT, NOSTMT);
    }
  }

  // --- C-write: col = lane&15 (n), row = kq*4 + reg (m)
  float* op = out + (long)(m0 + wm * 128 + kq * 4) * 256 + wn * 64 + lm;
#pragma unroll
  for (int mi = 0; mi < 8; ++mi) {
#pragma unroll
    for (int ni = 0; ni < 4; ++ni) {
      float* p = op + (long)mi * 16 * 256 + ni * 16;
      f32x4 v = acc[mi][ni];
      p[0] = v[0];
      p[256] = v[1];
      p[512] = v[2];
      p[768] = v[3];
    }
  }
}

// ---------- fallback (round-1 verified path) if ws too small for xpad ----------
__global__ __launch_bounds__(256) void conv_gemm_fb_k(
    const float* __restrict__ x, const u16* __restrict__ wp, float* __restrict__ out) {
  __shared__ u16 As[128 * 40];
  __shared__ u16 Bs[128 * 40];
  const int tid = threadIdx.x;
  const int m0 = blockIdx.x * 128;
  const int n0 = blockIdx.y * 128;
  const int cc = tid & 3;
  const int r0 = tid >> 2;
  const int gm0 = m0 + r0;
  const int gm1 = gm0 + 64;
  const int pix0 = gm0 % 3136, oh0 = pix0 / 56, ow0 = pix0 % 56;
  const int pix1 = gm1 % 3136, oh1 = pix1 / 56, ow1 = pix1 % 56;
  const int lane = tid & 63;
  const int wv = tid >> 6;
  const int wm = wv & 1, wn = wv >> 1;
  const int lm = lane & 15, kq = lane >> 4;
  const int aoff = (wm * 64 + lm) * 40 + kq * 8;
  const int boff = (wn * 64 + lm) * 40 + kq * 8;
  u16* as0 = As + r0 * 40 + cc * 8;
  u16* as1 = As + (r0 + 64) * 40 + cc * 8;
  u16* bs0 = Bs + r0 * 40 + cc * 8;
  u16* bs1 = Bs + (r0 + 64) * 40 + cc * 8;
  const u16* wr0 = wp + (long)(n0 + r0) * KTOT + cc * 8;
  const u16* wr1 = wr0 + (long)64 * KTOT;
  f32x4 acc[4][4] = {};
  for (int khw = 0; khw < 9; ++khw) {
    const int dh = khw / 3 - 1;
    const int dw = khw % 3 - 1;
    const bool v0 = ((unsigned)(oh0 + dh) < 56u) && ((unsigned)(ow0 + dw) < 56u);
    const bool v1 = ((unsigned)(oh1 + dh) < 56u) && ((unsigned)(ow1 + dw) < 56u);
    const long p0 = ((long)gm0 + dh * 56 + dw) * 256 + cc * 8;
    const long p1 = ((long)gm1 + dh * 56 + dw) * 256 + cc * 8;
    const u16* wk0 = wr0 + khw * 256;
    const u16* wk1 = wr1 + khw * 256;
    for (int ct = 0; ct < 8; ++ct) {
      const int ci0 = ct * 32;
      u16x8 a0 = {0,0,0,0,0,0,0,0}, a1 = {0,0,0,0,0,0,0,0};
      float4 l0 = make_float4(0,0,0,0), h0 = make_float4(0,0,0,0);
      float4 l1 = make_float4(0,0,0,0), h1 = make_float4(0,0,0,0);
      if (v0) { l0 = *(const float4*)(x + p0 + ci0); h0 = *(const float4*)(x + p0 + ci0 + 4); }
      if (v1) { l1 = *(const float4*)(x + p1 + ci0); h1 = *(const float4*)(x + p1 + ci0 + 4); }
      a0[0]=f2bf(l0.x); a0[1]=f2bf(l0.y); a0[2]=f2bf(l0.z); a0[3]=f2bf(l0.w);
      a0[4]=f2bf(h0.x); a0[5]=f2bf(h0.y); a0[6]=f2bf(h0.z); a0[7]=f2bf(h0.w);
      a1[0]=f2bf(l1.x); a1[1]=f2bf(l1.y); a1[2]=f2bf(l1.z); a1[3]=f2bf(l1.w);
      a1[4]=f2bf(h1.x); a1[5]=f2bf(h1.y); a1[6]=f2bf(h1.z); a1[7]=f2bf(h1.w);
      u16x8 b0 = *(const u16x8*)(wk0 + ci0);
      u16x8 b1 = *(const u16x8*)(wk1 + ci0);
      __syncthreads();
      *(u16x8*)as0 = a0; *(u16x8*)as1 = a1;
      *(u16x8*)bs0 = b0; *(u16x8*)bs1 = b1;
      __syncthreads();
      bf16x8 av[4], bvv[4];
#pragma unroll
      for (int i = 0; i < 4; ++i) av[i] = *(const bf16x8*)(As + aoff + i * 640);
#pragma unroll
      for (int i = 0; i < 4; ++i) bvv[i] = *(const bf16x8*)(Bs + boff + i * 640);
#pragma unroll
      for (int mi = 0; mi < 4; ++mi)
#pragma unroll
        for (int ni = 0; ni < 4; ++ni)
          acc[mi][ni] = __builtin_amdgcn_mfma_f32_16x16x32_bf16(av[mi], bvv[ni], acc[mi][ni], 0, 0, 0);
    }
  }
  float* op = out + (long)(m0 + wm * 64 + kq * 4) * 256 + n0 + wn * 64 + lm;
#pragma unroll
  for (int mi = 0; mi < 4; ++mi)
#pragma unroll
    for (int ni = 0; ni < 4; ++ni) {
      float* p = op + (long)mi * 16 * 256 + ni * 16;
      f32x4 v = acc[mi][ni];
      p[0] = v[0]; p[256] = v[1]; p[512] = v[2]; p[768] = v[3];
    }
}

extern "C" void kernel_launch(void* const* d_in, const int* in_sizes, int n_in,
                              void* d_out, int out_size, void* d_ws, size_t ws_size,
                              hipStream_t stream) {
  const float* x = (const float*)d_in[0];
  const float* w = (const float*)d_in[1];
  const float* mask = (const float*)d_in[2];
  float* out = (float*)d_out;

  float* scale = (float*)d_ws;                       // 1024 B + pad
  u16* wp = (u16*)((char*)d_ws + 1088);              // 1,179,648 B  [f][k] bf16
  u16* xpad = (u16*)((char*)d_ws + 1088 + 1179648);  // 55,115,776 B padded bf16 x
  const size_t xpad_bytes = (size_t)32 * IMG_PAD * 2;
  const size_t need = 1088 + 1179648 + xpad_bytes;

  (void)hipMemsetAsync(d_ws, 0, 1088, stream);
  scale_accum_k<<<36, 256, 0, stream>>>(w, scale);
  pack_w_k<<<dim3(72, 2), 256, 0, stream>>>(w, mask, scale, wp);
  if (ws_size >= need) {
    fill_xpad3_k<<<dim3(58, 32), 256, 0, stream>>>(x, xpad);
    conv_gemm9_k<<<392, 512, 0, stream>>>(xpad, wp, out);
  } else {
    conv_gemm_fb_k<<<dim3(784, 2), 256, 0, stream>>>(x, wp, out);
  }
}

// Round 7
// 337.730 us; speedup vs baseline: 1.0203x; 1.0203x over previous
//
#include <hip/hip_runtime.h>

typedef unsigned short u16;
typedef u16 u16x8 __attribute__((ext_vector_type(8)));
typedef __bf16 bf16x8 __attribute__((ext_vector_type(8)));
typedef float f32x4 __attribute__((ext_vector_type(4)));

#define NPIX 100352           // 32*56*56
#define KTOT 2304             // 3*3*256
#define IMG_PAD (58 * 58 * 256)

static __device__ __forceinline__ u16 f2bf(float f) {
  unsigned u = __float_as_uint(f);
  return (u16)((u + 0x7fffu + ((u >> 16) & 1u)) >> 16);
}

static __device__ __forceinline__ void gld_lds16(const u16* g, u16* l) {
  __builtin_amdgcn_global_load_lds(
      (const __attribute__((address_space(1))) void*)g,
      (__attribute__((address_space(3))) void*)l, 16, 0, 0);
}

// A-panel k-offset (u16) for K-tile kt: halo offset of khw + 64*(kt&3)
static __device__ __forceinline__ int ka_of(int kt) {
  const int khw = kt >> 2;                 // 0..8
  const int q = (khw * 11) >> 5;           // khw/3 for 0..8
  const int r = khw - q * 3;               // khw%3
  return (q * 58 + r - 59) * 256 + (kt & 3) * 64;
}

// ---------- scale[f] = sum_k |w[k][f]| ----------
__global__ void scale_accum_k(const float* __restrict__ w, float* __restrict__ scale) {
  const int t = threadIdx.x;
  const float* p = w + (long)blockIdx.x * 64 * 256 + t;
  float acc = 0.f;
#pragma unroll
  for (int e = 0; e < 64; ++e) acc += fabsf(p[(long)e * 256]);
  atomicAdd(&scale[t], acc);
}

// ---------- wp[f][k] = bf16( scale[f]/2304 * sign(w[k][f]) * mask[k][f] ) ----------
__global__ void pack_w_k(const float* __restrict__ w, const float* __restrict__ mask,
                         const float* __restrict__ ssum, u16* __restrict__ wp) {
  __shared__ u16 t[128][33];
  const int k0 = blockIdx.x * 32;
  const int f0 = blockIdx.y * 128;
  const int tid = threadIdx.x;
#pragma unroll
  for (int i = 0; i < 16; ++i) {
    int idx = tid + i * 256;
    int kk = idx >> 7;
    int ff = idx & 127;
    long g = (long)(k0 + kk) * 256 + f0 + ff;
    float wv = w[g];
    float mv = mask[g];
    float sc = ssum[f0 + ff] * (1.0f / 2304.0f);
    float sg = (wv > 0.f) ? 1.f : ((wv < 0.f) ? -1.f : 0.f);
    t[ff][kk] = f2bf(sc * sg * mv);
  }
  __syncthreads();
#pragma unroll
  for (int i = 0; i < 8; ++i) {
    int idx = tid + i * 256;
    int row = idx >> 4;
    int c = idx & 15;
    unsigned v = (unsigned)t[row][2 * c] | ((unsigned)t[row][2 * c + 1] << 16);
    *(unsigned*)(wp + (long)(f0 + row) * KTOT + k0 + 2 * c) = v;
  }
}

// ---------- x fp32 -> bf16 padded [32][58][58][256] — division-free 2D grid ----------
__global__ __launch_bounds__(256) void fill_xpad3_k(const float* __restrict__ x,
                                                    u16* __restrict__ xp) {
  const int img = blockIdx.y;
  const int ph = blockIdx.x;                       // 0..57
  u16* rowp = xp + ((img * 58 + ph) * 58) * 256;
  const bool irow = (ph >= 1 && ph <= 56);
  const float* xrow = x + ((long)img * 3136 + (ph - 1) * 56) * 256;
  for (int i = threadIdx.x; i < 58 * 32; i += 256) {
    const int pw = i >> 5;                         // 0..57
    const int c8 = (i & 31) * 8;                   // channel chunk base
    u16x8 v = {0, 0, 0, 0, 0, 0, 0, 0};
    if (irow && pw >= 1 && pw <= 56) {
      const float* s = xrow + (pw - 1) * 256 + c8;
      float4 a = *(const float4*)s;
      float4 b = *(const float4*)(s + 4);
      v[0] = f2bf(a.x); v[1] = f2bf(a.y); v[2] = f2bf(a.z); v[3] = f2bf(a.w);
      v[4] = f2bf(b.x); v[5] = f2bf(b.y); v[6] = f2bf(b.z); v[7] = f2bf(b.w);
    }
    *(u16x8*)(rowp + pw * 256 + c8) = v;
  }
}

// ---------- 256x256 8-phase conv, register-pipelined operand reads ----------
// R4 skeleton (128 KB dbuf, grid 392, vmcnt(4)@p3/p7) with the key change:
// ds_reads moved AFTER the opening barrier, prefetching the NEXT phase's A
// quadrant (alternate register set). MFMAs of phase p use registers loaded in
// phase p-1 -> LDS port serves reads WHILE matrix pipes run MFMAs (they were
// serialized by the barrier before: reads|bar|MFMA alternation, m-model fit
// 621+578 cyc/phase). B for K-tile kt+1 is read at p3/p7 after its publish
// barrier, placed after the MFMA cluster (WAR on live bv regs otherwise).
#define STAGE_A8(kt, h, buf) do { const int _ka = ka_of(kt); \
    gld_lds16(aptr[(h)*2]     + _ka, (buf) + ldso[(h)*2]); \
    gld_lds16(aptr[(h)*2 + 1] + _ka, (buf) + ldso[(h)*2 + 1]); } while (0)
#define STAGE_B8(kt, h, buf) do { const int _kb = (kt) * 64; \
    gld_lds16(bptr[(h)*2]     + _kb, (buf) + ldso[(h)*2]); \
    gld_lds16(bptr[(h)*2 + 1] + _kb, (buf) + ldso[(h)*2 + 1]); } while (0)

#define RD_AV(set, buf, q) do { \
    _Pragma("unroll") for (int f = 0; f < 2; ++f) \
      _Pragma("unroll") for (int ct = 0; ct < 2; ++ct) \
        av[set][f][ct] = *(const bf16x8*)((buf) + aB + pcq[ct] + (q) * 2048 + f * 1024); \
  } while (0)

#define RD_BV(set, buf) do { \
    _Pragma("unroll") for (int ni = 0; ni < 4; ++ni) \
      _Pragma("unroll") for (int ct = 0; ct < 2; ++ct) \
        bv[set][ni][ct] = *(const bf16x8*)((buf) + bB + pcq[ct] + ni * 1024); \
  } while (0)

#define MM(asid, bsid, pp) do { \
    _Pragma("unroll") for (int ct = 0; ct < 2; ++ct) \
      _Pragma("unroll") for (int f = 0; f < 2; ++f) \
        _Pragma("unroll") for (int ni = 0; ni < 4; ++ni) \
          acc[(pp)*2 + f][ni] = __builtin_amdgcn_mfma_f32_16x16x32_bf16( \
              av[asid][f][ct], bv[bsid][ni][ct], acc[(pp)*2 + f][ni], 0, 0, 0); \
  } while (0)

// phase: [stage, wait][bar][read-next (overlaps MFMA)][MFMA][post-read][bar]
#define PHASE2(pp, STAGE_STMT, WAIT_STMT, RDNEXT_STMT, POST_STMT, ASID, BSID) do { \
    STAGE_STMT; \
    WAIT_STMT; \
    __builtin_amdgcn_s_barrier(); \
    asm volatile("" ::: "memory"); \
    RDNEXT_STMT; \
    __builtin_amdgcn_sched_barrier(0); \
    __builtin_amdgcn_s_setprio(1); \
    MM(ASID, BSID, pp); \
    __builtin_amdgcn_s_setprio(0); \
    POST_STMT; \
    asm volatile("" ::: "memory"); \
    __builtin_amdgcn_s_barrier(); \
    asm volatile("" ::: "memory"); \
  } while (0)

#define VMC4 asm volatile("s_waitcnt vmcnt(4)" ::: "memory")
#define VMC0 asm volatile("s_waitcnt vmcnt(0)" ::: "memory")
#define NOSTMT do { } while (0)

__global__ __launch_bounds__(512, 2) void conv_gemm10_k(
    const u16* __restrict__ xpad, const u16* __restrict__ wp, float* __restrict__ out) {
  __shared__ u16 As0[256 * 64];   // 32 KB (even K-tiles)
  __shared__ u16 As1[256 * 64];   // 32 KB (odd K-tiles)
  __shared__ u16 Bs0[256 * 64];   // 32 KB
  __shared__ u16 Bs1[256 * 64];   // 32 KB

  const int tid = threadIdx.x;
  const int lane = tid & 63;
  const int wid = tid >> 6;         // 0..7

  // grid 392 = 8 XCD x 49, bijective swizzle (n0 == 0; B shared by all blocks)
  const int orig = blockIdx.x;
  const int swz = (orig & 7) * 49 + (orig >> 3);
  const int m0 = swz * 256;

  // --- staging map: octet o = (q>>1)*16 + (q&1)*8 + wid covers rows [o*8, o*8+8)
  const int lsub = lane >> 3;                       // 0..7 row-in-octet
  const int lc = (lane & 7) ^ lsub;                 // logical chunk (XOR swizzle)
  const u16* aptr[4];
  const u16* bptr[4];
  int ldso[4];
#pragma unroll
  for (int q = 0; q < 4; ++q) {
    const int o = (q >> 1) * 16 + (q & 1) * 8 + wid;   // 0..31
    const int row = o * 8 + lsub;                      // 0..255
    const int m = m0 + row;
    const int img = m / 3136, pix = m % 3136;
    aptr[q] = xpad + (long)img * IMG_PAD + ((pix / 56 + 1) * 58 + (pix % 56) + 1) * 256 + lc * 8;
    bptr[q] = wp + (long)row * KTOT + lc * 8;
    ldso[q] = o * 512;                                 // u16 units; DMA adds lane*16B
  }

  // --- MFMA lane mapping (verified layout)
  const int lm = lane & 15, kq = lane >> 4;
  const int wm = wid >> 2, wn = wid & 3;
  int pcq[2];
  pcq[0] = (kq ^ (lm & 7)) * 8;
  pcq[1] = ((4 + kq) ^ (lm & 7)) * 8;
  const int aB = (wm * 128 + lm) * 64;   // + q*2048 + f*1024 + pcq[ct]
  const int bB = (wn * 64 + lm) * 64;    // + ni*1024 + pcq[ct]

  f32x4 acc[8][4] = {};
  bf16x8 av[2][2][2];   // [set][f][ct]  — double-buffered A quadrant
  bf16x8 bv[2][4][2];   // [set][ni][ct] — double-buffered B tile

  // --- prologue: stage B(0),A(0)->buf0; B(1)->buf1; vmcnt(4) completes kt0 pair
  STAGE_B8(0, 0, Bs0); STAGE_B8(0, 1, Bs0);
  STAGE_A8(0, 0, As0); STAGE_A8(0, 1, As0);
  STAGE_B8(1, 0, Bs1); STAGE_B8(1, 1, Bs1);
  VMC4;
  __builtin_amdgcn_s_barrier();
  asm volatile("" ::: "memory");
  // pre-load first operands (kt=0, q0 + B(0)) — published by barrier above
  RD_AV(0, As0, 0);
  RD_BV(0, Bs0);

  // --- main: J = 0..16, kt pair (2J -> As0/Bs0, 2J+1 -> As1/Bs1)
  for (int J = 0; J < 17; ++J) {
    // kt even half (buf0), B set 0; av set = phase parity (p0:0, p1:1, ...)
    PHASE2(0, STAGE_A8(2 * J + 1, 0, As1), NOSTMT, RD_AV(1, As0, 1), NOSTMT, 0, 0);
    PHASE2(1, STAGE_A8(2 * J + 1, 1, As1), NOSTMT, RD_AV(0, As0, 2), NOSTMT, 1, 0);
    PHASE2(2, STAGE_B8(2 * J + 2, 0, Bs0), NOSTMT, RD_AV(1, As0, 3), NOSTMT, 0, 0);
    PHASE2(3, STAGE_B8(2 * J + 2, 1, Bs0), VMC4,   RD_AV(0, As1, 0), RD_BV(1, Bs1), 1, 0);
    // kt odd half (buf1), B set 1
    PHASE2(0, STAGE_A8(2 * J + 2, 0, As0), NOSTMT, RD_AV(1, As1, 1), NOSTMT, 0, 1);
    PHASE2(1, STAGE_A8(2 * J + 2, 1, As0), NOSTMT, RD_AV(0, As1, 2), NOSTMT, 1, 1);
    PHASE2(2, STAGE_B8(2 * J + 3, 0, Bs1), NOSTMT, RD_AV(1, As1, 3), NOSTMT, 0, 1);
    PHASE2(3, STAGE_B8(2 * J + 3, 1, Bs1), VMC4,   RD_AV(0, As0, 0), RD_BV(0, Bs0), 1, 1);
  }

  // --- epilogue: kt = 34 (buf0, B set 0), kt = 35 (buf1, B set 1)
  PHASE2(0, STAGE_A8(35, 0, As1), NOSTMT, RD_AV(1, As0, 1), NOSTMT, 0, 0);
  PHASE2(1, STAGE_A8(35, 1, As1), NOSTMT, RD_AV(0, As0, 2), NOSTMT, 1, 0);
  PHASE2(2, NOSTMT,               NOSTMT, RD_AV(1, As0, 3), NOSTMT, 0, 0);
  PHASE2(3, NOSTMT,               VMC0,   RD_AV(0, As1, 0), RD_BV(1, Bs1), 1, 0);
  PHASE2(0, NOSTMT,               NOSTMT, RD_AV(1, As1, 1), NOSTMT, 0, 1);
  PHASE2(1, NOSTMT,               NOSTMT, RD_AV(0, As1, 2), NOSTMT, 1, 1);
  PHASE2(2, NOSTMT,               NOSTMT, RD_AV(1, As1, 3), NOSTMT, 0, 1);
  PHASE2(3, NOSTMT,               NOSTMT, NOSTMT,           NOSTMT, 1, 1);

  // --- C-write: col = lane&15 (n), row = kq*4 + reg (m)
  float* op = out + (long)(m0 + wm * 128 + kq * 4) * 256 + wn * 64 + lm;
#pragma unroll
  for (int mi = 0; mi < 8; ++mi) {
#pragma unroll
    for (int ni = 0; ni < 4; ++ni) {
      float* p = op + (long)mi * 16 * 256 + ni * 16;
      f32x4 v = acc[mi][ni];
      p[0] = v[0];
      p[256] = v[1];
      p[512] = v[2];
      p[768] = v[3];
    }
  }
}

// ---------- fallback (round-1 verified path) if ws too small for xpad ----------
__global__ __launch_bounds__(256) void conv_gemm_fb_k(
    const float* __restrict__ x, const u16* __restrict__ wp, float* __restrict__ out) {
  __shared__ u16 As[128 * 40];
  __shared__ u16 Bs[128 * 40];
  const int tid = threadIdx.x;
  const int m0 = blockIdx.x * 128;
  const int n0 = blockIdx.y * 128;
  const int cc = tid & 3;
  const int r0 = tid >> 2;
  const int gm0 = m0 + r0;
  const int gm1 = gm0 + 64;
  const int pix0 = gm0 % 3136, oh0 = pix0 / 56, ow0 = pix0 % 56;
  const int pix1 = gm1 % 3136, oh1 = pix1 / 56, ow1 = pix1 % 56;
  const int lane = tid & 63;
  const int wv = tid >> 6;
  const int wm = wv & 1, wn = wv >> 1;
  const int lm = lane & 15, kq = lane >> 4;
  const int aoff = (wm * 64 + lm) * 40 + kq * 8;
  const int boff = (wn * 64 + lm) * 40 + kq * 8;
  u16* as0 = As + r0 * 40 + cc * 8;
  u16* as1 = As + (r0 + 64) * 40 + cc * 8;
  u16* bs0 = Bs + r0 * 40 + cc * 8;
  u16* bs1 = Bs + (r0 + 64) * 40 + cc * 8;
  const u16* wr0 = wp + (long)(n0 + r0) * KTOT + cc * 8;
  const u16* wr1 = wr0 + (long)64 * KTOT;
  f32x4 acc[4][4] = {};
  for (int khw = 0; khw < 9; ++khw) {
    const int dh = khw / 3 - 1;
    const int dw = khw % 3 - 1;
    const bool v0 = ((unsigned)(oh0 + dh) < 56u) && ((unsigned)(ow0 + dw) < 56u);
    const bool v1 = ((unsigned)(oh1 + dh) < 56u) && ((unsigned)(ow1 + dw) < 56u);
    const long p0 = ((long)gm0 + dh * 56 + dw) * 256 + cc * 8;
    const long p1 = ((long)gm1 + dh * 56 + dw) * 256 + cc * 8;
    const u16* wk0 = wr0 + khw * 256;
    const u16* wk1 = wr1 + khw * 256;
    for (int ct = 0; ct < 8; ++ct) {
      const int ci0 = ct * 32;
      u16x8 a0 = {0,0,0,0,0,0,0,0}, a1 = {0,0,0,0,0,0,0,0};
      float4 l0 = make_float4(0,0,0,0), h0 = make_float4(0,0,0,0);
      float4 l1 = make_float4(0,0,0,0), h1 = make_float4(0,0,0,0);
      if (v0) { l0 = *(const float4*)(x + p0 + ci0); h0 = *(const float4*)(x + p0 + ci0 + 4); }
      if (v1) { l1 = *(const float4*)(x + p1 + ci0); h1 = *(const float4*)(x + p1 + ci0 + 4); }
      a0[0]=f2bf(l0.x); a0[1]=f2bf(l0.y); a0[2]=f2bf(l0.z); a0[3]=f2bf(l0.w);
      a0[4]=f2bf(h0.x); a0[5]=f2bf(h0.y); a0[6]=f2bf(h0.z); a0[7]=f2bf(h0.w);
      a1[0]=f2bf(l1.x); a1[1]=f2bf(l1.y); a1[2]=f2bf(l1.z); a1[3]=f2bf(l1.w);
      a1[4]=f2bf(h1.x); a1[5]=f2bf(h1.y); a1[6]=f2bf(h1.z); a1[7]=f2bf(h1.w);
      u16x8 b0 = *(const u16x8*)(wk0 + ci0);
      u16x8 b1 = *(const u16x8*)(wk1 + ci0);
      __syncthreads();
      *(u16x8*)as0 = a0; *(u16x8*)as1 = a1;
      *(u16x8*)bs0 = b0; *(u16x8*)bs1 = b1;
      __syncthreads();
      bf16x8 avv[4], bvv[4];
#pragma unroll
      for (int i = 0; i < 4; ++i) avv[i] = *(const bf16x8*)(As + aoff + i * 640);
#pragma unroll
      for (int i = 0; i < 4; ++i) bvv[i] = *(const bf16x8*)(Bs + boff + i * 640);
#pragma unroll
      for (int mi = 0; mi < 4; ++mi)
#pragma unroll
        for (int ni = 0; ni < 4; ++ni)
          acc[mi][ni] = __builtin_amdgcn_mfma_f32_16x16x32_bf16(avv[mi], bvv[ni], acc[mi][ni], 0, 0, 0);
    }
  }
  float* op = out + (long)(m0 + wm * 64 + kq * 4) * 256 + n0 + wn * 64 + lm;
#pragma unroll
  for (int mi = 0; mi < 4; ++mi)
#pragma unroll
    for (int ni = 0; ni < 4; ++ni) {
      float* p = op + (long)mi * 16 * 256 + ni * 16;
      f32x4 v = acc[mi][ni];
      p[0] = v[0]; p[256] = v[1]; p[512] = v[2]; p[768] = v[3];
    }
}

extern "C" void kernel_launch(void* const* d_in, const int* in_sizes, int n_in,
                              void* d_out, int out_size, void* d_ws, size_t ws_size,
                              hipStream_t stream) {
  const float* x = (const float*)d_in[0];
  const float* w = (const float*)d_in[1];
  const float* mask = (const float*)d_in[2];
  float* out = (float*)d_out;

  float* scale = (float*)d_ws;                       // 1024 B + pad
  u16* wp = (u16*)((char*)d_ws + 1088);              // 1,179,648 B  [f][k] bf16
  u16* xpad = (u16*)((char*)d_ws + 1088 + 1179648);  // 55,115,776 B padded bf16 x
  const size_t xpad_bytes = (size_t)32 * IMG_PAD * 2;
  const size_t need = 1088 + 1179648 + xpad_bytes;

  (void)hipMemsetAsync(d_ws, 0, 1088, stream);
  scale_accum_k<<<36, 256, 0, stream>>>(w, scale);
  pack_w_k<<<dim3(72, 2), 256, 0, stream>>>(w, mask, scale, wp);
  if (ws_size >= need) {
    fill_xpad3_k<<<dim3(58, 32), 256, 0, stream>>>(x, xpad);
    conv_gemm10_k<<<392, 512, 0, stream>>>(xpad, wp, out);
  } else {
    conv_gemm_fb_k<<<dim3(784, 2), 256, 0, stream>>>(x, wp, out);
  }
}